// Round 1
// baseline (118.655 us; speedup 1.0000x reference)
//
#include <hip/hip_runtime.h>
#include <math.h>

// ChamferLoss: B=4, N=8192, M=8192, D=3, K=1.
// out = mean over 32768 queries of clamp(min_m ||q - r_m||^2, 0).
//
// Kernel 1: grid (BN/(BQ*QPT), SPLITS). Each block: 256 threads x 4 queries,
//   stages 512 refs (x,y,z,r2) in LDS, computes per-query partial min over its
//   ref split: min_r (r2 - 2 q.r), adds q2 + clamps at the end, stores to ws.
// Kernel 2: min across splits per query, sum, block-reduce, atomicAdd(mean).

#define BQ   256   // threads per block
#define QPT  4     // queries per thread
#define TILE 512   // refs staged in LDS per tile (8 KB as float4)

__global__ __launch_bounds__(BQ) void chamfer_partial_min(
    const float* __restrict__ query,   // [BN, 3]
    const float* __restrict__ ref,     // [M, 3]
    float* __restrict__ partial,       // [splits, BN]
    int BN, int refsPerSplit)
{
    __shared__ float4 lds[TILE];
    const int tid   = threadIdx.x;
    const int qbase = blockIdx.x * (BQ * QPT);
    const int split = blockIdx.y;
    const int rbase = split * refsPerSplit;

    float m2x[QPT], m2y[QPT], m2z[QPT], q2[QPT], dmin[QPT];
    int qid[QPT];
#pragma unroll
    for (int j = 0; j < QPT; ++j) {
        int q = qbase + tid + j * BQ;
        qid[j] = q;
        float qx = query[q * 3 + 0];
        float qy = query[q * 3 + 1];
        float qz = query[q * 3 + 2];
        m2x[j] = -2.0f * qx;
        m2y[j] = -2.0f * qy;
        m2z[j] = -2.0f * qz;
        q2[j]  = qx * qx + qy * qy + qz * qz;
        dmin[j] = INFINITY;
    }

    for (int t0 = 0; t0 < refsPerSplit; t0 += TILE) {
        __syncthreads();   // protect LDS reuse across tiles
#pragma unroll
        for (int i = tid; i < TILE; i += BQ) {
            int r = rbase + t0 + i;
            float rx = ref[r * 3 + 0];
            float ry = ref[r * 3 + 1];
            float rz = ref[r * 3 + 2];
            lds[i] = make_float4(rx, ry, rz, rx * rx + ry * ry + rz * rz);
        }
        __syncthreads();

#pragma unroll 4
        for (int i = 0; i < TILE; ++i) {
            float4 r = lds[i];
#pragma unroll
            for (int j = 0; j < QPT; ++j) {
                float t = fmaf(m2x[j], r.x, r.w);   // r2 - 2qx*rx
                t = fmaf(m2y[j], r.y, t);
                t = fmaf(m2z[j], r.z, t);
                dmin[j] = fminf(dmin[j], t);
            }
        }
    }

#pragma unroll
    for (int j = 0; j < QPT; ++j) {
        float d = q2[j] + dmin[j];
        partial[split * BN + qid[j]] = fmaxf(d, 0.0f);
    }
}

__global__ __launch_bounds__(BQ) void chamfer_reduce(
    const float* __restrict__ partial,  // [splits, BN]
    float* __restrict__ out,
    int BN, int splits, float invCount)
{
    int gtid   = blockIdx.x * blockDim.x + threadIdx.x;
    int stride = gridDim.x * blockDim.x;
    float sum = 0.0f;
    for (int q = gtid; q < BN; q += stride) {
        float m = partial[q];
        for (int s = 1; s < splits; ++s)
            m = fminf(m, partial[s * BN + q]);
        sum += m;
    }
    // wave-64 shuffle reduce
    for (int off = 32; off > 0; off >>= 1)
        sum += __shfl_down(sum, off, 64);
    __shared__ float wsum[BQ / 64];
    int lane = threadIdx.x & 63;
    int wid  = threadIdx.x >> 6;
    if (lane == 0) wsum[wid] = sum;
    __syncthreads();
    if (threadIdx.x == 0) {
        float s = 0.0f;
#pragma unroll
        for (int w = 0; w < BQ / 64; ++w) s += wsum[w];
        atomicAdd(out, s * invCount);
    }
}

extern "C" void kernel_launch(void* const* d_in, const int* in_sizes, int n_in,
                              void* d_out, int out_size, void* d_ws, size_t ws_size,
                              hipStream_t stream) {
    const float* query = (const float*)d_in[0];  // [B*N, 3]
    const float* ref   = (const float*)d_in[1];  // [M, 3]
    // d_in[2] is K == 1 (compile-time assumption: K=1 -> plain min)

    const int BN = in_sizes[0] / 3;   // 32768
    const int M  = in_sizes[1] / 3;   // 8192

    float* out     = (float*)d_out;
    float* partial = (float*)d_ws;

    // Choose the largest power-of-2 split count whose partial buffer fits ws.
    int splits = 16;
    while (splits > 1 && (size_t)splits * (size_t)BN * sizeof(float) > ws_size)
        splits >>= 1;
    int refsPerSplit = M / splits;    // multiple of TILE for splits<=16

    hipMemsetAsync(d_out, 0, sizeof(float), stream);

    dim3 grid(BN / (BQ * QPT), splits);
    chamfer_partial_min<<<grid, BQ, 0, stream>>>(query, ref, partial, BN, refsPerSplit);

    chamfer_reduce<<<dim3(16), BQ, 0, stream>>>(partial, out, BN, splits,
                                                1.0f / (float)BN);
}

// Round 2
// 97.068 us; speedup vs baseline: 1.2224x; 1.2224x over previous
//
#include <hip/hip_runtime.h>
#include <math.h>

// ChamferLoss: B=4, N=8192, M=8192, D=3, K=1.
// out = mean over 32768 queries of clamp(min_m ||q - r_m||^2, 0).
//
// K1: grid (BN/(BQ*QPT), SPLITS); 256 thr x 16 queries each; refs staged in
//     LDS pre-transposed into pair layout (x0,x1,y0,y1)/(z0,z1,r20,r21) so the
//     inner loop is 2 broadcast ds_read_b128 + 16x(3 v_pk_fma_f32 + min) per
//     ref-pair. Partial per-split mins -> ws.
// K2: one thread per query: min across splits, clamp, block-reduce, atomicAdd.

typedef __attribute__((ext_vector_type(2))) float f2;
typedef __attribute__((ext_vector_type(4))) float f4;

#define BQ   256   // threads per block
#define QPT  16    // queries per thread
#define TILE 128   // refs per LDS tile

__global__ __launch_bounds__(BQ, 2) void chamfer_partial_min(
    const float* __restrict__ query,   // [BN, 3]
    const float* __restrict__ ref,     // [M, 3]
    float* __restrict__ partial,       // [splits, BN]
    int BN, int refsPerSplit)
{
    __shared__ f4 ldsA[TILE / 2];   // (x0, x1, y0, y1) per ref pair
    __shared__ f4 ldsB[TILE / 2];   // (z0, z1, r20, r21) per ref pair

    const int tid   = threadIdx.x;
    const int qbase = blockIdx.x * (BQ * QPT);
    const int split = blockIdx.y;
    const int rbase = split * refsPerSplit;

    float m2x[QPT], m2y[QPT], m2z[QPT], q2[QPT];
    f2 dmin[QPT];
#pragma unroll
    for (int j = 0; j < QPT; ++j) {
        int q = qbase + tid + j * BQ;
        float qx = query[q * 3 + 0];
        float qy = query[q * 3 + 1];
        float qz = query[q * 3 + 2];
        m2x[j] = -2.0f * qx;
        m2y[j] = -2.0f * qy;
        m2z[j] = -2.0f * qz;
        q2[j]  = qx * qx + qy * qy + qz * qz;
        dmin[j].x = INFINITY;
        dmin[j].y = INFINITY;
    }

    for (int t0 = 0; t0 < refsPerSplit; t0 += TILE) {
        __syncthreads();
        if (tid < TILE) {
            int r = rbase + t0 + tid;
            float rx = ref[r * 3 + 0];
            float ry = ref[r * 3 + 1];
            float rz = ref[r * 3 + 2];
            float r2 = rx * rx + ry * ry + rz * rz;
            int p = tid >> 1, s = tid & 1;
            float* A  = (float*)&ldsA[p];
            float* Bp = (float*)&ldsB[p];
            A[0 + s]  = rx;  A[2 + s]  = ry;
            Bp[0 + s] = rz;  Bp[2 + s] = r2;
        }
        __syncthreads();

#pragma unroll 2
        for (int i = 0; i < TILE / 2; ++i) {
            f4 xy = ldsA[i];
            f4 zr = ldsB[i];
            f2 rx = xy.xy, ry = xy.zw;
            f2 rz = zr.xy, r2 = zr.zw;
#pragma unroll
            for (int j = 0; j < QPT; ++j) {
                f2 bx = {m2x[j], m2x[j]};
                f2 by = {m2y[j], m2y[j]};
                f2 bz = {m2z[j], m2z[j]};
                f2 t = __builtin_elementwise_fma(bx, rx, r2);
                t = __builtin_elementwise_fma(by, ry, t);
                t = __builtin_elementwise_fma(bz, rz, t);
                dmin[j] = __builtin_elementwise_min(dmin[j], t);
            }
        }
    }

#pragma unroll
    for (int j = 0; j < QPT; ++j) {
        int q = qbase + tid + j * BQ;
        float d = fminf(dmin[j].x, dmin[j].y) + q2[j];
        partial[split * BN + q] = fmaxf(d, 0.0f);
    }
}

__global__ __launch_bounds__(BQ) void chamfer_reduce(
    const float* __restrict__ partial,  // [splits, BN]
    float* __restrict__ out,
    int BN, int splits, float invCount)
{
    int q = blockIdx.x * blockDim.x + threadIdx.x;
    float sum = 0.0f;
    if (q < BN) {
        float m = partial[q];
        for (int s = 1; s < splits; ++s)
            m = fminf(m, partial[s * BN + q]);
        sum = m;
    }
    // wave-64 shuffle reduce
    for (int off = 32; off > 0; off >>= 1)
        sum += __shfl_down(sum, off, 64);
    __shared__ float wsum[BQ / 64];
    int lane = threadIdx.x & 63;
    int wid  = threadIdx.x >> 6;
    if (lane == 0) wsum[wid] = sum;
    __syncthreads();
    if (threadIdx.x == 0) {
        float s = 0.0f;
#pragma unroll
        for (int w = 0; w < BQ / 64; ++w) s += wsum[w];
        atomicAdd(out, s * invCount);
    }
}

extern "C" void kernel_launch(void* const* d_in, const int* in_sizes, int n_in,
                              void* d_out, int out_size, void* d_ws, size_t ws_size,
                              hipStream_t stream) {
    const float* query = (const float*)d_in[0];  // [B*N, 3]
    const float* ref   = (const float*)d_in[1];  // [M, 3]
    // d_in[2] is K == 1 (K=1 -> plain min)

    const int BN = in_sizes[0] / 3;   // 32768
    const int M  = in_sizes[1] / 3;   // 8192

    float* out     = (float*)d_out;
    float* partial = (float*)d_ws;

    int splits = 64;
    while (splits > 1 && ((size_t)splits * (size_t)BN * sizeof(float) > ws_size ||
                          (M / splits) % 2 != 0 || M % splits != 0))
        splits >>= 1;
    int refsPerSplit = M / splits;    // 128 for M=8192, splits=64

    hipMemsetAsync(d_out, 0, sizeof(float), stream);

    dim3 grid(BN / (BQ * QPT), splits);
    chamfer_partial_min<<<grid, BQ, 0, stream>>>(query, ref, partial, BN, refsPerSplit);

    chamfer_reduce<<<dim3((BN + BQ - 1) / BQ), BQ, 0, stream>>>(
        partial, out, BN, splits, 1.0f / (float)BN);
}

// Round 3
// 96.054 us; speedup vs baseline: 1.2353x; 1.0106x over previous
//
#include <hip/hip_runtime.h>
#include <math.h>

// ChamferLoss: B=4, N=8192, M=8192, D=3, K=1.
// out = mean over 32768 queries of clamp(min_m ||q - r_m||^2, 0).
//
// Timed region is dominated by 2x ~41us harness ws-poison fills (~85us fixed).
// Controllable part: K1 (partial min) + K2 (cross-split min + mean).
//
// K1: grid (BN/(BQ*QPT), SPLITS); 256 thr x 16 queries; 128 refs/split staged
//     in LDS pair-transposed (x0,x1,y0,y1)/(z0,z1,r20,r21). Inner loop per
//     ref-pair per query: 3 v_pk_fma_f32 + 1 v_min3_f32 = 2 instr/eval.
//     -2q pre-splatted into f2 regs at init (no per-iter movs).
// K2: one thread per query: min across splits, clamp, block-reduce, atomicAdd.

typedef __attribute__((ext_vector_type(2))) float f2;
typedef __attribute__((ext_vector_type(4))) float f4;

#define BQ   256   // threads per block
#define QPT  16    // queries per thread
#define TILE 128   // refs per LDS tile

__global__ __launch_bounds__(BQ, 2) void chamfer_partial_min(
    const float* __restrict__ query,   // [BN, 3]
    const float* __restrict__ ref,     // [M, 3]
    float* __restrict__ partial,       // [splits, BN]
    int BN, int refsPerSplit)
{
    __shared__ f4 ldsA[TILE / 2];   // (x0, x1, y0, y1) per ref pair
    __shared__ f4 ldsB[TILE / 2];   // (z0, z1, r20, r21) per ref pair

    const int tid   = threadIdx.x;
    const int qbase = blockIdx.x * (BQ * QPT);
    const int split = blockIdx.y;
    const int rbase = split * refsPerSplit;

    f2 bx[QPT], by[QPT], bz[QPT];   // pre-splatted -2*q
    float q2[QPT], dmin[QPT];
#pragma unroll
    for (int j = 0; j < QPT; ++j) {
        int q = qbase + tid + j * BQ;
        float qx = query[q * 3 + 0];
        float qy = query[q * 3 + 1];
        float qz = query[q * 3 + 2];
        float mx = -2.0f * qx, my = -2.0f * qy, mz = -2.0f * qz;
        bx[j].x = mx; bx[j].y = mx;
        by[j].x = my; by[j].y = my;
        bz[j].x = mz; bz[j].y = mz;
        q2[j]  = qx * qx + qy * qy + qz * qz;
        dmin[j] = INFINITY;
    }

    for (int t0 = 0; t0 < refsPerSplit; t0 += TILE) {
        __syncthreads();
        if (tid < TILE) {
            int r = rbase + t0 + tid;
            float rx = ref[r * 3 + 0];
            float ry = ref[r * 3 + 1];
            float rz = ref[r * 3 + 2];
            float r2 = rx * rx + ry * ry + rz * rz;
            int p = tid >> 1, s = tid & 1;
            float* A  = (float*)&ldsA[p];
            float* Bp = (float*)&ldsB[p];
            A[0 + s]  = rx;  A[2 + s]  = ry;
            Bp[0 + s] = rz;  Bp[2 + s] = r2;
        }
        __syncthreads();

#pragma unroll 2
        for (int i = 0; i < TILE / 4; ++i) {   // quad of refs = 2 LDS pairs
            f4 xy0 = ldsA[2 * i],     zr0 = ldsB[2 * i];
            f4 xy1 = ldsA[2 * i + 1], zr1 = ldsB[2 * i + 1];
#pragma unroll
            for (int j = 0; j < QPT; ++j) {
                f2 t0 = __builtin_elementwise_fma(bx[j], xy0.xy, zr0.zw);
                t0 = __builtin_elementwise_fma(by[j], xy0.zw, t0);
                t0 = __builtin_elementwise_fma(bz[j], zr0.xy, t0);
                f2 t1 = __builtin_elementwise_fma(bx[j], xy1.xy, zr1.zw);
                t1 = __builtin_elementwise_fma(by[j], xy1.zw, t1);
                t1 = __builtin_elementwise_fma(bz[j], zr1.xy, t1);
                dmin[j] = fminf(fminf(t0.x, t0.y), dmin[j]);  // v_min3_f32
                dmin[j] = fminf(fminf(t1.x, t1.y), dmin[j]);  // v_min3_f32
            }
        }
    }

#pragma unroll
    for (int j = 0; j < QPT; ++j) {
        int q = qbase + tid + j * BQ;
        float d = dmin[j] + q2[j];
        partial[split * BN + q] = fmaxf(d, 0.0f);
    }
}

__global__ __launch_bounds__(BQ) void chamfer_reduce(
    const float* __restrict__ partial,  // [splits, BN]
    float* __restrict__ out,
    int BN, int splits, float invCount)
{
    int q = blockIdx.x * blockDim.x + threadIdx.x;
    float sum = 0.0f;
    if (q < BN) {
        float m = partial[q];
        for (int s = 1; s < splits; ++s)
            m = fminf(m, partial[s * BN + q]);
        sum = m;
    }
    // wave-64 shuffle reduce
    for (int off = 32; off > 0; off >>= 1)
        sum += __shfl_down(sum, off, 64);
    __shared__ float wsum[BQ / 64];
    int lane = threadIdx.x & 63;
    int wid  = threadIdx.x >> 6;
    if (lane == 0) wsum[wid] = sum;
    __syncthreads();
    if (threadIdx.x == 0) {
        float s = 0.0f;
#pragma unroll
        for (int w = 0; w < BQ / 64; ++w) s += wsum[w];
        atomicAdd(out, s * invCount);
    }
}

extern "C" void kernel_launch(void* const* d_in, const int* in_sizes, int n_in,
                              void* d_out, int out_size, void* d_ws, size_t ws_size,
                              hipStream_t stream) {
    const float* query = (const float*)d_in[0];  // [B*N, 3]
    const float* ref   = (const float*)d_in[1];  // [M, 3]
    // d_in[2] is K == 1 (K=1 -> plain min)

    const int BN = in_sizes[0] / 3;   // 32768
    const int M  = in_sizes[1] / 3;   // 8192

    float* out     = (float*)d_out;
    float* partial = (float*)d_ws;

    int splits = 64;
    while (splits > 1 && ((size_t)splits * (size_t)BN * sizeof(float) > ws_size ||
                          (M / splits) % 4 != 0 || M % splits != 0))
        splits >>= 1;
    int refsPerSplit = M / splits;    // 128 for M=8192, splits=64

    hipMemsetAsync(d_out, 0, sizeof(float), stream);

    dim3 grid(BN / (BQ * QPT), splits);
    chamfer_partial_min<<<grid, BQ, 0, stream>>>(query, ref, partial, BN, refsPerSplit);

    chamfer_reduce<<<dim3((BN + BQ - 1) / BQ), BQ, 0, stream>>>(
        partial, out, BN, splits, 1.0f / (float)BN);
}

// Round 4
// 85.340 us; speedup vs baseline: 1.3904x; 1.1255x over previous
//
#include <hip/hip_runtime.h>
#include <math.h>

// ChamferLoss: B=4, N=8192, M=8192, D=3, K=1.
// out = mean over 32768 queries of clamp(min_m ||q - r_m||^2, 0).
//
// Timed region model (verified across R1-R3): ~82-84us of harness ws-poison
// fills (2 x 41us, 256MiB each at ~6.5TB/s, HBM-bound, not controllable)
// + k1 + k2 + launch overhead (~12-14us controllable).
//
// K1: grid (BN/(BQ*QPT), SPLITS); 256 thr x 16 queries; 128 refs/split staged
//     in LDS pair-transposed (x0,x1,y0,y1)/(z0,z1,r20,r21). Inner loop per
//     ref-quad per query: 6 v_pk_fma_f32 + 2 v_min3_f32 (forced via asm)
//     = 2.0 instr/eval. VALU-issue floor ~6.8us at 2 blocks/CU.
// K2: one thread per query: min across splits, clamp, block-reduce, atomicAdd.

typedef __attribute__((ext_vector_type(2))) float f2;
typedef __attribute__((ext_vector_type(4))) float f4;

#define BQ   256   // threads per block
#define QPT  16    // queries per thread
#define TILE 128   // refs per LDS tile

__device__ __forceinline__ float min3f(float a, float b, float c) {
    float d;
    asm("v_min3_f32 %0, %1, %2, %3" : "=v"(d) : "v"(a), "v"(b), "v"(c));
    return d;
}

__global__ __launch_bounds__(BQ, 2) void chamfer_partial_min(
    const float* __restrict__ query,   // [BN, 3]
    const float* __restrict__ ref,     // [M, 3]
    float* __restrict__ partial,       // [splits, BN]
    int BN, int refsPerSplit)
{
    __shared__ f4 ldsA[TILE / 2];   // (x0, x1, y0, y1) per ref pair
    __shared__ f4 ldsB[TILE / 2];   // (z0, z1, r20, r21) per ref pair

    const int tid   = threadIdx.x;
    const int qbase = blockIdx.x * (BQ * QPT);
    const int split = blockIdx.y;
    const int rbase = split * refsPerSplit;

    f2 bx[QPT], by[QPT], bz[QPT];   // pre-splatted -2*q
    float q2[QPT], dmin[QPT];
#pragma unroll
    for (int j = 0; j < QPT; ++j) {
        int q = qbase + tid + j * BQ;
        float qx = query[q * 3 + 0];
        float qy = query[q * 3 + 1];
        float qz = query[q * 3 + 2];
        float mx = -2.0f * qx, my = -2.0f * qy, mz = -2.0f * qz;
        bx[j].x = mx; bx[j].y = mx;
        by[j].x = my; by[j].y = my;
        bz[j].x = mz; bz[j].y = mz;
        q2[j]  = qx * qx + qy * qy + qz * qz;
        dmin[j] = INFINITY;
    }

    for (int t0 = 0; t0 < refsPerSplit; t0 += TILE) {
        __syncthreads();
        if (tid < TILE) {
            int r = rbase + t0 + tid;
            float rx = ref[r * 3 + 0];
            float ry = ref[r * 3 + 1];
            float rz = ref[r * 3 + 2];
            float r2 = rx * rx + ry * ry + rz * rz;
            int p = tid >> 1, s = tid & 1;
            float* A  = (float*)&ldsA[p];
            float* Bp = (float*)&ldsB[p];
            A[0 + s]  = rx;  A[2 + s]  = ry;
            Bp[0 + s] = rz;  Bp[2 + s] = r2;
        }
        __syncthreads();

#pragma unroll 2
        for (int i = 0; i < TILE / 4; ++i) {   // quad of refs = 2 LDS pairs
            f4 xy0 = ldsA[2 * i],     zr0 = ldsB[2 * i];
            f4 xy1 = ldsA[2 * i + 1], zr1 = ldsB[2 * i + 1];
#pragma unroll
            for (int j = 0; j < QPT; ++j) {
                f2 t0 = __builtin_elementwise_fma(bx[j], xy0.xy, zr0.zw);
                t0 = __builtin_elementwise_fma(by[j], xy0.zw, t0);
                t0 = __builtin_elementwise_fma(bz[j], zr0.xy, t0);
                f2 t1 = __builtin_elementwise_fma(bx[j], xy1.xy, zr1.zw);
                t1 = __builtin_elementwise_fma(by[j], xy1.zw, t1);
                t1 = __builtin_elementwise_fma(bz[j], zr1.xy, t1);
                dmin[j] = min3f(t0.x, t0.y, min3f(t1.x, t1.y, dmin[j]));
            }
        }
    }

#pragma unroll
    for (int j = 0; j < QPT; ++j) {
        int q = qbase + tid + j * BQ;
        float d = dmin[j] + q2[j];
        partial[split * BN + q] = fmaxf(d, 0.0f);
    }
}

__global__ __launch_bounds__(BQ) void chamfer_reduce(
    const float* __restrict__ partial,  // [splits, BN]
    float* __restrict__ out,
    int BN, int splits, float invCount)
{
    int q = blockIdx.x * blockDim.x + threadIdx.x;
    float sum = 0.0f;
    if (q < BN) {
        float m = partial[q];
#pragma unroll 8
        for (int s = 1; s < splits; ++s)
            m = fminf(m, partial[s * BN + q]);
        sum = m;
    }
    // wave-64 shuffle reduce
    for (int off = 32; off > 0; off >>= 1)
        sum += __shfl_down(sum, off, 64);
    __shared__ float wsum[BQ / 64];
    int lane = threadIdx.x & 63;
    int wid  = threadIdx.x >> 6;
    if (lane == 0) wsum[wid] = sum;
    __syncthreads();
    if (threadIdx.x == 0) {
        float s = 0.0f;
#pragma unroll
        for (int w = 0; w < BQ / 64; ++w) s += wsum[w];
        atomicAdd(out, s * invCount);
    }
}

extern "C" void kernel_launch(void* const* d_in, const int* in_sizes, int n_in,
                              void* d_out, int out_size, void* d_ws, size_t ws_size,
                              hipStream_t stream) {
    const float* query = (const float*)d_in[0];  // [B*N, 3]
    const float* ref   = (const float*)d_in[1];  // [M, 3]
    // d_in[2] is K == 1 (K=1 -> plain min)

    const int BN = in_sizes[0] / 3;   // 32768
    const int M  = in_sizes[1] / 3;   // 8192

    float* out     = (float*)d_out;
    float* partial = (float*)d_ws;

    int splits = 64;
    while (splits > 1 && ((size_t)splits * (size_t)BN * sizeof(float) > ws_size ||
                          (M / splits) % 4 != 0 || M % splits != 0))
        splits >>= 1;
    int refsPerSplit = M / splits;    // 128 for M=8192, splits=64

    hipMemsetAsync(d_out, 0, sizeof(float), stream);

    dim3 grid(BN / (BQ * QPT), splits);
    chamfer_partial_min<<<grid, BQ, 0, stream>>>(query, ref, partial, BN, refsPerSplit);

    chamfer_reduce<<<dim3((BN + BQ - 1) / BQ), BQ, 0, stream>>>(
        partial, out, BN, splits, 1.0f / (float)BN);
}